// Round 1
// baseline (3736.745 us; speedup 1.0000x reference)
//
#include <hip/hip_runtime.h>
#include <stdint.h>

#define B_ 64
#define T_ 512
#define IN_ 128
#define H_ 256
#define G_ 768
#define M0_ (B_*T_)   // 32768

typedef _Float16 f16;
typedef _Float16 f16x2 __attribute__((ext_vector_type(2)));
typedef _Float16 half8 __attribute__((ext_vector_type(8)));
typedef float f32x4 __attribute__((ext_vector_type(4)));

// ---------------- projection GEMM: xg[dir][m][n] = A[m][:]·W[dir][n][:] + bias[dir][n] ----------------
// A: M0 x K (f32 if AF32 else f16) row-major; W: 2 x 768 x K f32 (B^T layout); out: 2 x M0 x 768 f16
template<bool AF32>
__global__ __launch_bounds__(256) void k_proj(
    const float* __restrict__ Af, const f16* __restrict__ Ah,
    const float* __restrict__ W, const float* __restrict__ bias,
    f16* __restrict__ out, int K)
{
  int dir = blockIdx.z;
  const float* Wd = W + (size_t)dir*G_*K;
  const float* bd = bias + dir*G_;
  f16* outd = out + (size_t)dir*M0_*G_;
  int m0 = blockIdx.x*128, n0 = blockIdx.y*128;
  int tid = threadIdx.x, lane = tid & 63, wv = tid >> 6;
  int wm = wv >> 1, wn = wv & 1;
  int l15 = lane & 15, quad = lane >> 4;

  __shared__ f16 As[128][72];   // +8 pad breaks bank conflicts
  __shared__ f16 Ws[128][72];

  f32x4 acc[4][4];
  #pragma unroll
  for (int i = 0; i < 4; i++)
    #pragma unroll
    for (int j = 0; j < 4; j++) acc[i][j] = (f32x4){0.f,0.f,0.f,0.f};

  int lr = tid >> 3, lk = (tid & 7) * 8;
  for (int k0 = 0; k0 < K; k0 += 64){
    #pragma unroll
    for (int it = 0; it < 4; it++){
      int row = lr + it*32;
      // A tile
      if (AF32){
        const float* p = &Af[(size_t)(m0+row)*K + k0 + lk];
        float4 v0 = *(const float4*)p;
        float4 v1 = *(const float4*)(p + 4);
        *(half8*)&As[row][lk] = (half8){(f16)v0.x,(f16)v0.y,(f16)v0.z,(f16)v0.w,
                                        (f16)v1.x,(f16)v1.y,(f16)v1.z,(f16)v1.w};
      } else {
        *(uint4*)&As[row][lk] = *(const uint4*)&Ah[(size_t)(m0+row)*K + k0 + lk];
      }
      // W tile (always f32 -> f16)
      {
        const float* p = &Wd[(size_t)(n0+row)*K + k0 + lk];
        float4 v0 = *(const float4*)p;
        float4 v1 = *(const float4*)(p + 4);
        *(half8*)&Ws[row][lk] = (half8){(f16)v0.x,(f16)v0.y,(f16)v0.z,(f16)v0.w,
                                        (f16)v1.x,(f16)v1.y,(f16)v1.z,(f16)v1.w};
      }
    }
    __syncthreads();
    #pragma unroll
    for (int kk = 0; kk < 64; kk += 32){
      half8 af[4], bf[4];
      #pragma unroll
      for (int mi = 0; mi < 4; mi++) af[mi] = *(const half8*)&As[wm*64 + mi*16 + l15][kk + quad*8];
      #pragma unroll
      for (int ni = 0; ni < 4; ni++) bf[ni] = *(const half8*)&Ws[wn*64 + ni*16 + l15][kk + quad*8];
      #pragma unroll
      for (int mi = 0; mi < 4; mi++)
        #pragma unroll
        for (int ni = 0; ni < 4; ni++)
          acc[mi][ni] = __builtin_amdgcn_mfma_f32_16x16x32_f16(af[mi], bf[ni], acc[mi][ni], 0, 0, 0);
    }
    __syncthreads();
  }
  #pragma unroll
  for (int mi = 0; mi < 4; mi++){
    #pragma unroll
    for (int ni = 0; ni < 4; ni++){
      int m = m0 + wm*64 + mi*16 + quad*4;
      int n = n0 + wn*64 + ni*16 + l15;
      float bn = bd[n];
      #pragma unroll
      for (int r = 0; r < 4; r++)
        outd[(size_t)(m+r)*G_ + n] = (f16)(acc[mi][ni][r] + bn);
    }
  }
}

// ---------------- persistent-register GRU via broadcast-M MFMA ----------------
// One WG per (batch, dir), 512 thr = 8 waves. Wave w owns hidden units [w*32, w*32+32).
// Whh rows for those units (r,z,n = 6 16-col tiles x 8 k-frags) live as MFMA B-fragments
// in registers (AGPR-friendly: only consumed by MFMA). Every A-row of the 16x16x32 MFMA
// is loaded with the same h-slice (A-frag address ignores lane&15), so each lane's acc[.][0]
// holds the full 256-dot for its column -> no cross-lane reduce, no hg LDS round-trip.
// h state is a per-lane f32 register; only a 2x256 f16 double-buffer lives in LDS.
// One raw barrier per step (lgkmcnt only -- y stores / xg loads never drain vmcnt).
__global__ __launch_bounds__(512, 2) void k_rnn(
    const f16* __restrict__ xg, const float* __restrict__ whh,
    const float* __restrict__ bhh, f16* __restrict__ y)
{
  int b = blockIdx.x, dir = blockIdx.y;
  int tid = threadIdx.x, lane = tid & 63, wv = tid >> 6;
  int col = lane & 15, kg = lane >> 4;   // B-frag: col, k-group of 8
  int u = wv*32 + (lane & 31);           // owned unit (valid for lane<32)

  const f16* cxg = xg + ((size_t)dir*M0_ + (size_t)b*T_)*G_;
  const float* wbase = whh + (size_t)dir*G_*H_;
  const float* bh = bhh + dir*G_;
  f16* yb = y + (size_t)b*T_*512 + dir*256;

  __shared__ __align__(16) f16 hbuf[2][256];

  // ---- resident B-fragments: tile t in {r0,r1,z0,z1,n0,n1}, 8 k-frags each ----
  // wf[t*8+kf][j] = Whh[nb(t)+col][kf*32 + kg*8 + j]  (f32 -> f16 once)
  half8 wf[48];
  float bias6[6];
  #pragma unroll
  for (int t = 0; t < 6; t++){
    int nb = (t>>1)*256 + wv*32 + (t&1)*16;
    const float* wrow = wbase + (size_t)(nb + col)*H_;
    #pragma unroll
    for (int kf = 0; kf < 8; kf++){
      const float4* p = (const float4*)(wrow + kf*32 + kg*8);
      float4 v0 = p[0], v1 = p[1];
      wf[t*8+kf] = (half8){(f16)v0.x,(f16)v0.y,(f16)v0.z,(f16)v0.w,
                           (f16)v1.x,(f16)v1.y,(f16)v1.z,(f16)v1.w};
    }
    bias6[t] = bh[nb + col];             // bhh folded into accumulator init
  }

  float hreg = 0.f;
  if (tid < 256) hbuf[0][tid] = (f16)0.f;
  __syncthreads();

  for (int s = 0; s < T_; ++s){
    int tt = dir ? (T_-1-s) : s;
    int cur = s & 1, nxt = cur ^ 1;

    // xg for the owned unit -- issued early, consumed after the MFMA block
    float xr = 0.f, xz = 0.f, xn = 0.f;
    if (lane < 32){
      const f16* xp = cxg + (size_t)tt*G_ + u;
      xr = (float)xp[0]; xz = (float)xp[256]; xn = (float)xp[512];
    }

    f32x4 acc[6];
    #pragma unroll
    for (int t = 0; t < 6; t++)
      acc[t] = (f32x4){bias6[t], bias6[t], bias6[t], bias6[t]};

    // A-frags: same h slice in every M-row (address independent of col).
    // 4 distinct 16B addresses per read -> pure broadcast, conflict-free.
    const f16* hp = &hbuf[cur][kg*8];
    half8 a0 = *(const half8*)hp;        // depth-2 pipeline over k-frags
    #pragma unroll
    for (int kf = 0; kf < 8; kf++){
      half8 ac = a0;
      if (kf < 7) a0 = *(const half8*)(hp + (kf+1)*32);
      #pragma unroll
      for (int t = 0; t < 6; t++)
        acc[t] = __builtin_amdgcn_mfma_f32_16x16x32_f16(ac, wf[t*8+kf], acc[t], 0, 0, 0);
    }

    if (lane < 32){
      int sel = lane >> 4;               // which 16-col sub-tile of the 32 units
      float sr = acc[0+sel][0];
      float sz = acc[2+sel][0];
      float sn = acc[4+sel][0];
      float ar = xr + sr; ar = fminf(fmaxf(ar, -30.f), 30.f);
      float az = xz + sz; az = fminf(fmaxf(az, -30.f), 30.f);
      float r = 1.f/(1.f + __expf(-ar));
      float z = 1.f/(1.f + __expf(-az));
      float an = xn + r*sn; an = fminf(fmaxf(an, -15.f), 15.f);
      float e = __expf(2.f*an);
      float nn = (e - 1.f)/(e + 1.f);
      hreg = (1.f - z)*nn + z*hreg;
      hbuf[nxt][u] = (f16)hreg;
      yb[(size_t)tt*512 + u] = (f16)hreg;
    }
    // raw barrier: drain LDS only; y-store / xg-load latency stays off the
    // critical path (no cross-thread consumer of those vmem ops).
    asm volatile("s_waitcnt lgkmcnt(0)\n\ts_barrier" ::: "memory");
  }
}

// ---------------- MLP head: one WG per batch, all f32 ----------------
__global__ __launch_bounds__(256) void k_head(
    const f16* __restrict__ y,
    const float* __restrict__ W1, const float* __restrict__ b1,
    const float* __restrict__ W2, const float* __restrict__ b2,
    const float* __restrict__ W3, const float* __restrict__ b3,
    const float* __restrict__ W4, const float* __restrict__ b4,
    float* __restrict__ out)
{
  int b = blockIdx.x, tid = threadIdx.x;
  __shared__ float a0[512], a1[128], a2[64], a3[256];
  const f16* yr = y + ((size_t)b*T_ + (T_-1))*512;
  a0[tid] = (float)yr[tid]; a0[tid+256] = (float)yr[tid+256];
  __syncthreads();
  if (tid < 128){
    float s = b1[tid];
    const float4* w = (const float4*)(W1 + (size_t)tid*512);
    #pragma unroll 8
    for (int c = 0; c < 128; c++){
      float4 v = w[c];
      s += v.x*a0[c*4] + v.y*a0[c*4+1] + v.z*a0[c*4+2] + v.w*a0[c*4+3];
    }
    a1[tid] = fmaxf(s, 0.f);
  }
  __syncthreads();
  if (tid < 64){
    float s = b2[tid];
    const float4* w = (const float4*)(W2 + (size_t)tid*128);
    #pragma unroll
    for (int c = 0; c < 32; c++){
      float4 v = w[c];
      s += v.x*a1[c*4] + v.y*a1[c*4+1] + v.z*a1[c*4+2] + v.w*a1[c*4+3];
    }
    a2[tid] = fmaxf(s, 0.f);
  }
  __syncthreads();
  if (tid < 256){
    float s = b3[tid];
    const float4* w = (const float4*)(W3 + (size_t)tid*64);
    #pragma unroll
    for (int c = 0; c < 16; c++){
      float4 v = w[c];
      s += v.x*a2[c*4] + v.y*a2[c*4+1] + v.z*a2[c*4+2] + v.w*a2[c*4+3];
    }
    a3[tid] = fmaxf(s, 0.f);
  }
  __syncthreads();
  if (tid < 50){
    float s = b4[tid];
    const float4* w = (const float4*)(W4 + (size_t)tid*256);
    #pragma unroll
    for (int c = 0; c < 64; c++){
      float4 v = w[c];
      s += v.x*a3[c*4] + v.y*a3[c*4+1] + v.z*a3[c*4+2] + v.w*a3[c*4+3];
    }
    out[b*50 + tid] = s;
  }
}

extern "C" void kernel_launch(void* const* d_in, const int* in_sizes, int n_in,
                              void* d_out, int out_size, void* d_ws, size_t ws_size,
                              hipStream_t stream)
{
  const float* x    = (const float*)d_in[0];
  const float* Wih0 = (const float*)d_in[1];
  const float* Whh0 = (const float*)d_in[2];
  const float* bih0 = (const float*)d_in[3];
  const float* bhh0 = (const float*)d_in[4];
  const float* Wih  = (const float*)d_in[5];
  const float* Whh  = (const float*)d_in[6];
  const float* bih  = (const float*)d_in[7];
  const float* bhh  = (const float*)d_in[8];
  const float* W1 = (const float*)d_in[9];
  const float* b1 = (const float*)d_in[10];
  const float* W2 = (const float*)d_in[11];
  const float* b2 = (const float*)d_in[12];
  const float* W3 = (const float*)d_in[13];
  const float* b3 = (const float*)d_in[14];
  const float* W4 = (const float*)d_in[15];
  const float* b4 = (const float*)d_in[16];

  char* ws = (char*)d_ws;
  f16* xg = (f16*)ws;                          // 2*M0*768*2 = 100,663,296 B
  f16* y  = (f16*)(ws + 100663296ull);         //   M0*512*2 =  33,554,432 B
  // total exactly 128 MiB; nothing written beyond.

  // layer 0 (A = x, f32, K=128)
  k_proj<true ><<<dim3(M0_/128, 6, 2), dim3(256), 0, stream>>>(x, nullptr, Wih0, bih0, xg, IN_);
  k_rnn        <<<dim3(B_, 2),         dim3(512), 0, stream>>>(xg, Whh0, bhh0, y);
  // layer 1 (A = y, f16, K=512)
  k_proj<false><<<dim3(M0_/128, 6, 2), dim3(256), 0, stream>>>(nullptr, y, Wih, bih, xg, 2*H_);
  k_rnn        <<<dim3(B_, 2),         dim3(512), 0, stream>>>(xg, Whh, bhh, y);
  // layer 2
  k_proj<false><<<dim3(M0_/128, 6, 2), dim3(256), 0, stream>>>(nullptr, y, Wih + 1ull*2*G_*(2*H_), bih + 2*G_, xg, 2*H_);
  k_rnn        <<<dim3(B_, 2),         dim3(512), 0, stream>>>(xg, Whh + 1ull*2*G_*H_, bhh + 2*G_, y);

  k_head<<<dim3(B_), dim3(256), 0, stream>>>(y, W1, b1, W2, b2, W3, b3, W4, b4,
                                             (float*)d_out);
}

// Round 3
// 2659.882 us; speedup vs baseline: 1.4049x; 1.4049x over previous
//
#include <hip/hip_runtime.h>
#include <stdint.h>

#define B_ 64
#define T_ 512
#define IN_ 128
#define H_ 256
#define G_ 768
#define M0_ (B_*T_)   // 32768

typedef _Float16 f16;
typedef _Float16 f16x2 __attribute__((ext_vector_type(2)));
typedef _Float16 half8 __attribute__((ext_vector_type(8)));
typedef float f32x4 __attribute__((ext_vector_type(4)));

// ---------------- projection GEMM: xg[dir][m][n] = A[m][:]·W[dir][n][:] + bias[dir][n] ----------------
// A: M0 x K (f32 if AF32 else f16) row-major; W: 2 x 768 x K f32 (B^T layout); out: 2 x M0 x 768 f16
template<bool AF32>
__global__ __launch_bounds__(256) void k_proj(
    const float* __restrict__ Af, const f16* __restrict__ Ah,
    const float* __restrict__ W, const float* __restrict__ bias,
    f16* __restrict__ out, int K)
{
  int dir = blockIdx.z;
  const float* Wd = W + (size_t)dir*G_*K;
  const float* bd = bias + dir*G_;
  f16* outd = out + (size_t)dir*M0_*G_;
  int m0 = blockIdx.x*128, n0 = blockIdx.y*128;
  int tid = threadIdx.x, lane = tid & 63, wv = tid >> 6;
  int wm = wv >> 1, wn = wv & 1;
  int l15 = lane & 15, quad = lane >> 4;

  __shared__ f16 As[128][72];   // +8 pad breaks bank conflicts
  __shared__ f16 Ws[128][72];

  f32x4 acc[4][4];
  #pragma unroll
  for (int i = 0; i < 4; i++)
    #pragma unroll
    for (int j = 0; j < 4; j++) acc[i][j] = (f32x4){0.f,0.f,0.f,0.f};

  int lr = tid >> 3, lk = (tid & 7) * 8;
  for (int k0 = 0; k0 < K; k0 += 64){
    #pragma unroll
    for (int it = 0; it < 4; it++){
      int row = lr + it*32;
      // A tile
      if (AF32){
        const float* p = &Af[(size_t)(m0+row)*K + k0 + lk];
        float4 v0 = *(const float4*)p;
        float4 v1 = *(const float4*)(p + 4);
        *(half8*)&As[row][lk] = (half8){(f16)v0.x,(f16)v0.y,(f16)v0.z,(f16)v0.w,
                                        (f16)v1.x,(f16)v1.y,(f16)v1.z,(f16)v1.w};
      } else {
        *(uint4*)&As[row][lk] = *(const uint4*)&Ah[(size_t)(m0+row)*K + k0 + lk];
      }
      // W tile (always f32 -> f16)
      {
        const float* p = &Wd[(size_t)(n0+row)*K + k0 + lk];
        float4 v0 = *(const float4*)p;
        float4 v1 = *(const float4*)(p + 4);
        *(half8*)&Ws[row][lk] = (half8){(f16)v0.x,(f16)v0.y,(f16)v0.z,(f16)v0.w,
                                        (f16)v1.x,(f16)v1.y,(f16)v1.z,(f16)v1.w};
      }
    }
    __syncthreads();
    #pragma unroll
    for (int kk = 0; kk < 64; kk += 32){
      half8 af[4], bf[4];
      #pragma unroll
      for (int mi = 0; mi < 4; mi++) af[mi] = *(const half8*)&As[wm*64 + mi*16 + l15][kk + quad*8];
      #pragma unroll
      for (int ni = 0; ni < 4; ni++) bf[ni] = *(const half8*)&Ws[wn*64 + ni*16 + l15][kk + quad*8];
      #pragma unroll
      for (int mi = 0; mi < 4; mi++)
        #pragma unroll
        for (int ni = 0; ni < 4; ni++)
          acc[mi][ni] = __builtin_amdgcn_mfma_f32_16x16x32_f16(af[mi], bf[ni], acc[mi][ni], 0, 0, 0);
    }
    __syncthreads();
  }
  #pragma unroll
  for (int mi = 0; mi < 4; mi++){
    #pragma unroll
    for (int ni = 0; ni < 4; ni++){
      int m = m0 + wm*64 + mi*16 + quad*4;
      int n = n0 + wn*64 + ni*16 + l15;
      float bn = bd[n];
      #pragma unroll
      for (int r = 0; r < 4; r++)
        outd[(size_t)(m+r)*G_ + n] = (f16)(acc[mi][ni][r] + bn);
    }
  }
}

// ---------------- persistent-register GRU via broadcast-M MFMA, 4-wave / 512-reg ----------------
// One WG of 256 thr (4 waves) per (batch, dir); 1 wave/SIMD -> full 512-reg budget, NO spill.
// Wave wv owns hidden units [wv*64, wv*64+64) = 12 tiles (3 gates x 4 col-tiles) x 8 k-frags.
// Weights live as 96 half8 MFMA B-fragments (384 regs) in the unified VGPR/AGPR file.
// Broadcast-M: every A-row of the 16x16x32 MFMA carries the same h slice, so lane L's
// acc[t][0] is the full 256-dot for col (L&15) of tile t -> no cross-lane reduce at all.
// Lane's owned unit u == tid (col = lane&15, col-tile = lane>>4): gate math runs on all
// 64 lanes, h state is a per-lane f32 register, xg is prefetched one full step ahead.
// One raw barrier per step (lgkmcnt only; xg loads / y stores never drain vmcnt).
__global__ __launch_bounds__(256, 1) void k_rnn(
    const f16* __restrict__ xg, const float* __restrict__ whh,
    const float* __restrict__ bhh, f16* __restrict__ y)
{
  int b = blockIdx.x, dir = blockIdx.y;
  int tid = threadIdx.x, lane = tid & 63, wv = tid >> 6;
  int col = lane & 15, kg = lane >> 4;   // fragment coords: col, k-group of 8

  const f16* cxg = xg + ((size_t)dir*M0_ + (size_t)b*T_)*G_;
  const float* wbase = whh + (size_t)dir*G_*H_;
  const float* bh = bhh + dir*G_;
  f16* yb = y + (size_t)b*T_*512 + dir*256;

  __shared__ __align__(16) f16 hbuf[2][256];

  // ---- resident B-fragments: tile t = gate*4 + coltile, 8 k-frags each ----
  // wf[t*8+kf][j] = Whh[gate*256 + wv*64 + coltile*16 + col][kf*32 + kg*8 + j]
  half8 wf[96];
  #pragma unroll
  for (int t = 0; t < 12; t++){
    int g = t >> 2, c = t & 3;
    const float* wrow = wbase + (size_t)(g*256 + wv*64 + c*16 + col)*H_;
    #pragma unroll
    for (int kf = 0; kf < 8; kf++){
      const float4* p = (const float4*)(wrow + kf*32 + kg*8);
      float4 v0 = p[0], v1 = p[1];
      wf[t*8+kf] = (half8){(f16)v0.x,(f16)v0.y,(f16)v0.z,(f16)v0.w,
                           (f16)v1.x,(f16)v1.y,(f16)v1.z,(f16)v1.w};
    }
  }

  float br = bh[tid], bz = bh[tid+256], bn = bh[tid+512];
  float hreg = 0.f;
  hbuf[0][tid] = (f16)0.f;
  __syncthreads();

  // xg prefetch pipeline: raw f16 regs, converted only at use (keeps the
  // implicit vmcnt wait one full step after issue -> HBM/L3 latency hidden)
  int tt0 = dir ? (T_-1) : 0;
  const f16* xp0 = cxg + (size_t)tt0*G_ + tid;
  f16 cxr = xp0[0], cxz = xp0[256], cxn = xp0[512];

  for (int s = 0; s < T_; ++s){
    int tt = dir ? (T_-1-s) : s;
    int cur = s & 1, nxt = cur ^ 1;

    // issue next step's xg loads now; consumed at loop tail (≈ full step later)
    f16 nxr = (f16)0.f, nxz = (f16)0.f, nxn = (f16)0.f;
    if (s + 1 < T_){
      int tn = dir ? (T_-2-s) : (s+1);
      const f16* xq = cxg + (size_t)tn*G_ + tid;
      nxr = xq[0]; nxz = xq[256]; nxn = xq[512];
    }

    // A-frags: same h slice in every M-row (address ignores col) -> pure broadcast.
    // Depth-2 rotate keeps every half8 name static (stays in registers).
    const f16* hp = &hbuf[cur][kg*8];
    f32x4 acc[12];
    half8 acur = *(const half8*)hp;
    half8 anxt = *(const half8*)(hp + 32);
    #pragma unroll
    for (int kf = 0; kf < 8; kf++){
      half8 ac = acur;
      acur = anxt;
      if (kf < 6) anxt = *(const half8*)(hp + (kf+2)*32);
      #pragma unroll
      for (int t = 0; t < 12; t++){
        if (kf == 0)
          acc[t] = __builtin_amdgcn_mfma_f32_16x16x32_f16(ac, wf[t*8+kf],
                     (f32x4){0.f,0.f,0.f,0.f}, 0, 0, 0);   // C = 0: no init pass
        else
          acc[t] = __builtin_amdgcn_mfma_f32_16x16x32_f16(ac, wf[t*8+kf], acc[t], 0, 0, 0);
      }
    }

    // lane's unit u = tid: col-tile select by kg via static cndmask tree
    float r0 = (kg & 1) ? acc[1][0] : acc[0][0];
    float r1 = (kg & 1) ? acc[3][0] : acc[2][0];
    float sr = (kg & 2) ? r1 : r0;
    float z0 = (kg & 1) ? acc[5][0] : acc[4][0];
    float z1 = (kg & 1) ? acc[7][0] : acc[6][0];
    float sz = (kg & 2) ? z1 : z0;
    float n0v = (kg & 1) ? acc[9][0]  : acc[8][0];
    float n1v = (kg & 1) ? acc[11][0] : acc[10][0];
    float sn = (kg & 2) ? n1v : n0v;

    float ar = (float)cxr + sr + br; ar = fminf(fmaxf(ar, -30.f), 30.f);
    float az = (float)cxz + sz + bz; az = fminf(fmaxf(az, -30.f), 30.f);
    float r = 1.f/(1.f + __expf(-ar));
    float z = 1.f/(1.f + __expf(-az));
    float an = (float)cxn + r*(sn + bn); an = fminf(fmaxf(an, -15.f), 15.f);
    float e = __expf(2.f*an);
    float nn = (e - 1.f)/(e + 1.f);
    hreg = (1.f - z)*nn + z*hreg;
    hbuf[nxt][tid] = (f16)hreg;
    yb[(size_t)tt*512 + tid] = (f16)hreg;

    // rotate prefetch regs (vmcnt wait lands here, ~full step after issue)
    cxr = nxr; cxz = nxz; cxn = nxn;

    // raw barrier: drain LDS only; vmem latency stays off the critical path
    asm volatile("s_waitcnt lgkmcnt(0)\n\ts_barrier" ::: "memory");
  }
}

// ---------------- MLP head: one WG per batch, all f32 ----------------
__global__ __launch_bounds__(256) void k_head(
    const f16* __restrict__ y,
    const float* __restrict__ W1, const float* __restrict__ b1,
    const float* __restrict__ W2, const float* __restrict__ b2,
    const float* __restrict__ W3, const float* __restrict__ b3,
    const float* __restrict__ W4, const float* __restrict__ b4,
    float* __restrict__ out)
{
  int b = blockIdx.x, tid = threadIdx.x;
  __shared__ float a0[512], a1[128], a2[64], a3[256];
  const f16* yr = y + ((size_t)b*T_ + (T_-1))*512;
  a0[tid] = (float)yr[tid]; a0[tid+256] = (float)yr[tid+256];
  __syncthreads();
  if (tid < 128){
    float s = b1[tid];
    const float4* w = (const float4*)(W1 + (size_t)tid*512);
    #pragma unroll 8
    for (int c = 0; c < 128; c++){
      float4 v = w[c];
      s += v.x*a0[c*4] + v.y*a0[c*4+1] + v.z*a0[c*4+2] + v.w*a0[c*4+3];
    }
    a1[tid] = fmaxf(s, 0.f);
  }
  __syncthreads();
  if (tid < 64){
    float s = b2[tid];
    const float4* w = (const float4*)(W2 + (size_t)tid*128);
    #pragma unroll
    for (int c = 0; c < 32; c++){
      float4 v = w[c];
      s += v.x*a1[c*4] + v.y*a1[c*4+1] + v.z*a1[c*4+2] + v.w*a1[c*4+3];
    }
    a2[tid] = fmaxf(s, 0.f);
  }
  __syncthreads();
  if (tid < 256){
    float s = b3[tid];
    const float4* w = (const float4*)(W3 + (size_t)tid*64);
    #pragma unroll
    for (int c = 0; c < 16; c++){
      float4 v = w[c];
      s += v.x*a2[c*4] + v.y*a2[c*4+1] + v.z*a2[c*4+2] + v.w*a2[c*4+3];
    }
    a3[tid] = fmaxf(s, 0.f);
  }
  __syncthreads();
  if (tid < 50){
    float s = b4[tid];
    const float4* w = (const float4*)(W4 + (size_t)tid*256);
    #pragma unroll
    for (int c = 0; c < 64; c++){
      float4 v = w[c];
      s += v.x*a3[c*4] + v.y*a3[c*4+1] + v.z*a3[c*4+2] + v.w*a3[c*4+3];
    }
    out[b*50 + tid] = s;
  }
}

extern "C" void kernel_launch(void* const* d_in, const int* in_sizes, int n_in,
                              void* d_out, int out_size, void* d_ws, size_t ws_size,
                              hipStream_t stream)
{
  const float* x    = (const float*)d_in[0];
  const float* Wih0 = (const float*)d_in[1];
  const float* Whh0 = (const float*)d_in[2];
  const float* bih0 = (const float*)d_in[3];
  const float* bhh0 = (const float*)d_in[4];
  const float* Wih  = (const float*)d_in[5];
  const float* Whh  = (const float*)d_in[6];
  const float* bih  = (const float*)d_in[7];
  const float* bhh  = (const float*)d_in[8];
  const float* W1 = (const float*)d_in[9];
  const float* b1 = (const float*)d_in[10];
  const float* W2 = (const float*)d_in[11];
  const float* b2 = (const float*)d_in[12];
  const float* W3 = (const float*)d_in[13];
  const float* b3 = (const float*)d_in[14];
  const float* W4 = (const float*)d_in[15];
  const float* b4 = (const float*)d_in[16];

  char* ws = (char*)d_ws;
  f16* xg = (f16*)ws;                          // 2*M0*768*2 = 100,663,296 B
  f16* y  = (f16*)(ws + 100663296ull);         //   M0*512*2 =  33,554,432 B
  // total exactly 128 MiB; nothing written beyond.

  // layer 0 (A = x, f32, K=128)
  k_proj<true ><<<dim3(M0_/128, 6, 2), dim3(256), 0, stream>>>(x, nullptr, Wih0, bih0, xg, IN_);
  k_rnn        <<<dim3(B_, 2),         dim3(256), 0, stream>>>(xg, Whh0, bhh0, y);
  // layer 1 (A = y, f16, K=512)
  k_proj<false><<<dim3(M0_/128, 6, 2), dim3(256), 0, stream>>>(nullptr, y, Wih, bih, xg, 2*H_);
  k_rnn        <<<dim3(B_, 2),         dim3(256), 0, stream>>>(xg, Whh, bhh, y);
  // layer 2
  k_proj<false><<<dim3(M0_/128, 6, 2), dim3(256), 0, stream>>>(nullptr, y, Wih + 1ull*2*G_*(2*H_), bih + 2*G_, xg, 2*H_);
  k_rnn        <<<dim3(B_, 2),         dim3(256), 0, stream>>>(xg, Whh + 1ull*2*G_*H_, bhh + 2*G_, y);

  k_head<<<dim3(B_), dim3(256), 0, stream>>>(y, W1, b1, W2, b2, W3, b3, W4, b4,
                                             (float*)d_out);
}

// Round 4
// 2054.122 us; speedup vs baseline: 1.8191x; 1.2949x over previous
//
#include <hip/hip_runtime.h>
#include <stdint.h>

#define B_ 64
#define T_ 512
#define IN_ 128
#define H_ 256
#define G_ 768
#define M0_ (B_*T_)   // 32768

typedef _Float16 f16;
typedef _Float16 f16x2 __attribute__((ext_vector_type(2)));
typedef _Float16 half8 __attribute__((ext_vector_type(8)));
typedef float f32x4 __attribute__((ext_vector_type(4)));

// ---------------- projection GEMM: xg[dir][m][n] = A[m][:]·W[dir][n][:] + bias[dir][n] ----------------
// A: M0 x K (f32 if AF32 else f16) row-major; W: 2 x 768 x K f32 (B^T layout); out: 2 x M0 x 768 f16
template<bool AF32>
__global__ __launch_bounds__(256) void k_proj(
    const float* __restrict__ Af, const f16* __restrict__ Ah,
    const float* __restrict__ W, const float* __restrict__ bias,
    f16* __restrict__ out, int K)
{
  int dir = blockIdx.z;
  const float* Wd = W + (size_t)dir*G_*K;
  const float* bd = bias + dir*G_;
  f16* outd = out + (size_t)dir*M0_*G_;
  int m0 = blockIdx.x*128, n0 = blockIdx.y*128;
  int tid = threadIdx.x, lane = tid & 63, wv = tid >> 6;
  int wm = wv >> 1, wn = wv & 1;
  int l15 = lane & 15, quad = lane >> 4;

  __shared__ f16 As[128][72];   // +8 pad breaks bank conflicts
  __shared__ f16 Ws[128][72];

  f32x4 acc[4][4];
  #pragma unroll
  for (int i = 0; i < 4; i++)
    #pragma unroll
    for (int j = 0; j < 4; j++) acc[i][j] = (f32x4){0.f,0.f,0.f,0.f};

  int lr = tid >> 3, lk = (tid & 7) * 8;
  for (int k0 = 0; k0 < K; k0 += 64){
    #pragma unroll
    for (int it = 0; it < 4; it++){
      int row = lr + it*32;
      // A tile
      if (AF32){
        const float* p = &Af[(size_t)(m0+row)*K + k0 + lk];
        float4 v0 = *(const float4*)p;
        float4 v1 = *(const float4*)(p + 4);
        *(half8*)&As[row][lk] = (half8){(f16)v0.x,(f16)v0.y,(f16)v0.z,(f16)v0.w,
                                        (f16)v1.x,(f16)v1.y,(f16)v1.z,(f16)v1.w};
      } else {
        *(uint4*)&As[row][lk] = *(const uint4*)&Ah[(size_t)(m0+row)*K + k0 + lk];
      }
      // W tile (always f32 -> f16)
      {
        const float* p = &Wd[(size_t)(n0+row)*K + k0 + lk];
        float4 v0 = *(const float4*)p;
        float4 v1 = *(const float4*)(p + 4);
        *(half8*)&Ws[row][lk] = (half8){(f16)v0.x,(f16)v0.y,(f16)v0.z,(f16)v0.w,
                                        (f16)v1.x,(f16)v1.y,(f16)v1.z,(f16)v1.w};
      }
    }
    __syncthreads();
    #pragma unroll
    for (int kk = 0; kk < 64; kk += 32){
      half8 af[4], bf[4];
      #pragma unroll
      for (int mi = 0; mi < 4; mi++) af[mi] = *(const half8*)&As[wm*64 + mi*16 + l15][kk + quad*8];
      #pragma unroll
      for (int ni = 0; ni < 4; ni++) bf[ni] = *(const half8*)&Ws[wn*64 + ni*16 + l15][kk + quad*8];
      #pragma unroll
      for (int mi = 0; mi < 4; mi++)
        #pragma unroll
        for (int ni = 0; ni < 4; ni++)
          acc[mi][ni] = __builtin_amdgcn_mfma_f32_16x16x32_f16(af[mi], bf[ni], acc[mi][ni], 0, 0, 0);
    }
    __syncthreads();
  }
  #pragma unroll
  for (int mi = 0; mi < 4; mi++){
    #pragma unroll
    for (int ni = 0; ni < 4; ni++){
      int m = m0 + wm*64 + mi*16 + quad*4;
      int n = n0 + wn*64 + ni*16 + l15;
      float bn = bd[n];
      #pragma unroll
      for (int r = 0; r < 4; r++)
        outd[(size_t)(m+r)*G_ + n] = (f16)(acc[mi][ni][r] + bn);
    }
  }
}

// ---------------- persistent-register GRU via broadcast-M MFMA, 8 waves @ 2 waves/EU ----------------
// One WG of 512 thr (8 waves) per (batch, dir). amdgpu_waves_per_eu(2,2) pins the register
// budget at exactly 256/wave so the occupancy heuristic cannot spill the weight file
// (rounds 1 & 3 showed the allocator targeting 4 / 2 waves/EU and spilling ~half the weights:
// VGPR_Count 128 / 228 vs demand 245 / 480).
// Wave wv owns hidden units [wv*32, wv*32+32): 6 tiles (3 gates x 2 col-tiles) x 8 k-frags
// = 48 half8 B-fragments = 192 VGPRs; acc = 6 x f32x4 (AGPR-native); total ~245 <= 256.
// Broadcast-M: every A-row of the 16x16x32 MFMA carries the same h slice, so each lane's
// acc[t][0] is the full 256-dot for its column -> no cross-lane reduce, no LDS round-trip.
// 2 waves/SIMD fill each other's MFMA issue gaps and hide LDS/gate latency.
// One raw barrier per step (lgkmcnt only; xg loads / y stores never drain vmcnt).
__global__ __launch_bounds__(512) __attribute__((amdgpu_waves_per_eu(2, 2)))
void k_rnn(
    const f16* __restrict__ xg, const float* __restrict__ whh,
    const float* __restrict__ bhh, f16* __restrict__ y)
{
  int b = blockIdx.x, dir = blockIdx.y;
  int tid = threadIdx.x, lane = tid & 63, wv = tid >> 6;
  int col = lane & 15, kg = lane >> 4;       // fragment coords: col, k-group of 8
  int u = wv*32 + (lane & 31);               // owned unit (lanes 32-63 mirror 0-31)

  const f16* cxg = xg + ((size_t)dir*M0_ + (size_t)b*T_)*G_;
  const float* wbase = whh + (size_t)dir*G_*H_;
  const float* bh = bhh + dir*G_;
  f16* yb = y + (size_t)b*T_*512 + dir*256;

  __shared__ __align__(16) f16 hbuf[2][256];

  // ---- resident B-fragments: tile t = gate*2 + coltile, 8 k-frags each ----
  // wf[t*8+kf][j] = Whh[gate*256 + wv*32 + coltile*16 + col][kf*32 + kg*8 + j]
  half8 wf[48];
  #pragma unroll
  for (int t = 0; t < 6; t++){
    int g = t >> 1, c = t & 1;
    const float* wrow = wbase + (size_t)(g*256 + wv*32 + c*16 + col)*H_;
    #pragma unroll
    for (int kf = 0; kf < 8; kf++){
      const float4* p = (const float4*)(wrow + kf*32 + kg*8);
      float4 v0 = p[0], v1 = p[1];
      wf[t*8+kf] = (half8){(f16)v0.x,(f16)v0.y,(f16)v0.z,(f16)v0.w,
                           (f16)v1.x,(f16)v1.y,(f16)v1.z,(f16)v1.w};
    }
  }

  float br = bh[u], bz = bh[u+256], bn = bh[u+512];
  float hreg = 0.f;
  if (tid < 256) hbuf[0][tid] = (f16)0.f;
  __syncthreads();

  // xg prefetch pipeline: raw f16 regs, converted only at use (keeps the
  // implicit vmcnt wait one full step after issue -> HBM/L3 latency hidden)
  int tt0 = dir ? (T_-1) : 0;
  const f16* xp0 = cxg + (size_t)tt0*G_ + u;
  f16 cxr = xp0[0], cxz = xp0[256], cxn = xp0[512];

  for (int s = 0; s < T_; ++s){
    int tt = dir ? (T_-1-s) : s;
    int cur = s & 1, nxt = cur ^ 1;

    // issue next step's xg loads now; consumed at loop tail (≈ full step later)
    f16 nxr = (f16)0.f, nxz = (f16)0.f, nxn = (f16)0.f;
    if (s + 1 < T_){
      int tn = dir ? (T_-2-s) : (s+1);
      const f16* xq = cxg + (size_t)tn*G_ + u;
      nxr = xq[0]; nxz = xq[256]; nxn = xq[512];
    }

    // A-frags: same h slice in every M-row (address ignores col) -> pure broadcast.
    // Depth-2 rotate keeps every half8 name static (stays in registers).
    const f16* hp = &hbuf[cur][kg*8];
    f32x4 acc[6];
    half8 acur = *(const half8*)hp;
    half8 anxt = *(const half8*)(hp + 32);
    #pragma unroll
    for (int kf = 0; kf < 8; kf++){
      half8 ac = acur;
      acur = anxt;
      if (kf < 6) anxt = *(const half8*)(hp + (kf+2)*32);
      #pragma unroll
      for (int t = 0; t < 6; t++){
        if (kf == 0)
          acc[t] = __builtin_amdgcn_mfma_f32_16x16x32_f16(ac, wf[t*8+kf],
                     (f32x4){0.f,0.f,0.f,0.f}, 0, 0, 0);   // C = 0: no init pass
        else
          acc[t] = __builtin_amdgcn_mfma_f32_16x16x32_f16(ac, wf[t*8+kf], acc[t], 0, 0, 0);
      }
    }

    // lane's unit u: coltile select c = (u>>4)&1 == (lane>>4)&1
    int c = (lane >> 4) & 1;
    float sr = c ? acc[1][0] : acc[0][0];
    float sz = c ? acc[3][0] : acc[2][0];
    float sn = c ? acc[5][0] : acc[4][0];

    float ar = (float)cxr + sr + br; ar = fminf(fmaxf(ar, -30.f), 30.f);
    float az = (float)cxz + sz + bz; az = fminf(fmaxf(az, -30.f), 30.f);
    float r = 1.f/(1.f + __expf(-ar));
    float z = 1.f/(1.f + __expf(-az));
    float an = (float)cxn + r*(sn + bn); an = fminf(fmaxf(an, -15.f), 15.f);
    float e = __expf(2.f*an);
    float nn = (e - 1.f)/(e + 1.f);
    hreg = (1.f - z)*nn + z*hreg;
    if (lane < 32){                          // lanes 32-63 hold duplicate values
      hbuf[nxt][u] = (f16)hreg;
      yb[(size_t)tt*512 + u] = (f16)hreg;
    }

    // rotate prefetch regs (vmcnt wait lands here, ~full step after issue)
    cxr = nxr; cxz = nxz; cxn = nxn;

    // raw barrier: drain LDS only; vmem latency stays off the critical path
    asm volatile("s_waitcnt lgkmcnt(0)\n\ts_barrier" ::: "memory");
  }
}

// ---------------- MLP head: one WG per batch, all f32 ----------------
__global__ __launch_bounds__(256) void k_head(
    const f16* __restrict__ y,
    const float* __restrict__ W1, const float* __restrict__ b1,
    const float* __restrict__ W2, const float* __restrict__ b2,
    const float* __restrict__ W3, const float* __restrict__ b3,
    const float* __restrict__ W4, const float* __restrict__ b4,
    float* __restrict__ out)
{
  int b = blockIdx.x, tid = threadIdx.x;
  __shared__ float a0[512], a1[128], a2[64], a3[256];
  const f16* yr = y + ((size_t)b*T_ + (T_-1))*512;
  a0[tid] = (float)yr[tid]; a0[tid+256] = (float)yr[tid+256];
  __syncthreads();
  if (tid < 128){
    float s = b1[tid];
    const float4* w = (const float4*)(W1 + (size_t)tid*512);
    #pragma unroll 8
    for (int c = 0; c < 128; c++){
      float4 v = w[c];
      s += v.x*a0[c*4] + v.y*a0[c*4+1] + v.z*a0[c*4+2] + v.w*a0[c*4+3];
    }
    a1[tid] = fmaxf(s, 0.f);
  }
  __syncthreads();
  if (tid < 64){
    float s = b2[tid];
    const float4* w = (const float4*)(W2 + (size_t)tid*128);
    #pragma unroll
    for (int c = 0; c < 32; c++){
      float4 v = w[c];
      s += v.x*a1[c*4] + v.y*a1[c*4+1] + v.z*a1[c*4+2] + v.w*a1[c*4+3];
    }
    a2[tid] = fmaxf(s, 0.f);
  }
  __syncthreads();
  if (tid < 256){
    float s = b3[tid];
    const float4* w = (const float4*)(W3 + (size_t)tid*64);
    #pragma unroll
    for (int c = 0; c < 16; c++){
      float4 v = w[c];
      s += v.x*a2[c*4] + v.y*a2[c*4+1] + v.z*a2[c*4+2] + v.w*a2[c*4+3];
    }
    a3[tid] = fmaxf(s, 0.f);
  }
  __syncthreads();
  if (tid < 50){
    float s = b4[tid];
    const float4* w = (const float4*)(W4 + (size_t)tid*256);
    #pragma unroll
    for (int c = 0; c < 64; c++){
      float4 v = w[c];
      s += v.x*a3[c*4] + v.y*a3[c*4+1] + v.z*a3[c*4+2] + v.w*a3[c*4+3];
    }
    out[b*50 + tid] = s;
  }
}

extern "C" void kernel_launch(void* const* d_in, const int* in_sizes, int n_in,
                              void* d_out, int out_size, void* d_ws, size_t ws_size,
                              hipStream_t stream)
{
  const float* x    = (const float*)d_in[0];
  const float* Wih0 = (const float*)d_in[1];
  const float* Whh0 = (const float*)d_in[2];
  const float* bih0 = (const float*)d_in[3];
  const float* bhh0 = (const float*)d_in[4];
  const float* Wih  = (const float*)d_in[5];
  const float* Whh  = (const float*)d_in[6];
  const float* bih  = (const float*)d_in[7];
  const float* bhh  = (const float*)d_in[8];
  const float* W1 = (const float*)d_in[9];
  const float* b1 = (const float*)d_in[10];
  const float* W2 = (const float*)d_in[11];
  const float* b2 = (const float*)d_in[12];
  const float* W3 = (const float*)d_in[13];
  const float* b3 = (const float*)d_in[14];
  const float* W4 = (const float*)d_in[15];
  const float* b4 = (const float*)d_in[16];

  char* ws = (char*)d_ws;
  f16* xg = (f16*)ws;                          // 2*M0*768*2 = 100,663,296 B
  f16* y  = (f16*)(ws + 100663296ull);         //   M0*512*2 =  33,554,432 B
  // total exactly 128 MiB; nothing written beyond.

  // layer 0 (A = x, f32, K=128)
  k_proj<true ><<<dim3(M0_/128, 6, 2), dim3(256), 0, stream>>>(x, nullptr, Wih0, bih0, xg, IN_);
  k_rnn        <<<dim3(B_, 2),         dim3(512), 0, stream>>>(xg, Whh0, bhh0, y);
  // layer 1 (A = y, f16, K=512)
  k_proj<false><<<dim3(M0_/128, 6, 2), dim3(256), 0, stream>>>(nullptr, y, Wih, bih, xg, 2*H_);
  k_rnn        <<<dim3(B_, 2),         dim3(512), 0, stream>>>(xg, Whh, bhh, y);
  // layer 2
  k_proj<false><<<dim3(M0_/128, 6, 2), dim3(256), 0, stream>>>(nullptr, y, Wih + 1ull*2*G_*(2*H_), bih + 2*G_, xg, 2*H_);
  k_rnn        <<<dim3(B_, 2),         dim3(512), 0, stream>>>(xg, Whh + 1ull*2*G_*H_, bhh + 2*G_, y);

  k_head<<<dim3(B_), dim3(256), 0, stream>>>(y, W1, b1, W2, b2, W3, b3, W4, b4,
                                             (float*)d_out);
}